// Round 2
// baseline (2376.494 us; speedup 1.0000x reference)
//
#include <hip/hip_runtime.h>
#include <hip/hip_bf16.h>
#include <math.h>

// Problem dims
#define VOCAB 50001
#define EDIM 256
#define HDIM 256          // per-direction hidden
#define GDIM 1024         // 4*HDIM gates
#define KTAG 9
#define NB 64             // batch
#define NT 256            // time

// workspace layout (float offsets)
static constexpr size_t XP_OFF   = 0;                                   // xproj [16384][2048]
static constexpr size_t WT_OFF   = XP_OFF + (size_t)16384 * 2048;       // wT4 [2][64][1024][4]
static constexpr size_t BIAS_OFF = WT_OFF + (size_t)2 * 64 * 1024 * 4;  // bias [2][1024]
static constexpr size_t HS_OFF   = BIAS_OFF + 2048;                     // hstore [16384][512]
static constexpr size_t EM_OFF   = HS_OFF + (size_t)16384 * 512;        // emissions [16384][9]

// ---------------------------------------------------------------------------
// Prep: transpose w_hh into [dir][k4][g][4] float4 layout for coalesced reads,
// and combined bias b_ih+b_hh.
__global__ __launch_bounds__(256) void k_prep(const float* __restrict__ wf,
                                              const float* __restrict__ wb,
                                              const float* __restrict__ bif,
                                              const float* __restrict__ bhf,
                                              const float* __restrict__ bib,
                                              const float* __restrict__ bhb,
                                              float* __restrict__ ws) {
    float* wt = ws + WT_OFF;
    float* bias = ws + BIAS_OFF;
    int tid = blockIdx.x * 256 + threadIdx.x;   // 512 blocks * 256 = 131072 = 2*64*1024
    int dir = tid >> 16;
    int rem = tid & 65535;
    int k4 = rem >> 10;
    int g = rem & 1023;
    const float* w = dir ? wb : wf;
    float4 v = *reinterpret_cast<const float4*>(w + (size_t)g * 256 + k4 * 4);
    *reinterpret_cast<float4*>(wt + ((size_t)dir * 65536 + (size_t)k4 * 1024 + g) * 4) = v;
    if (tid < 2048) {
        int d = tid >> 10, gg = tid & 1023;
        bias[tid] = d ? (bib[gg] + bhb[gg]) : (bif[gg] + bhf[gg]);
    }
}

// ---------------------------------------------------------------------------
// xproj GEMM: M=16384 rows (r = t*64+b, A row = embed[x[b,t]]), N=2048
// (w_ih_f rows 0..1023 | w_ih_b rows 1024..2047), K=256. fp32, 64x64 tiles.
#define BKC 32
__global__ __launch_bounds__(256) void k_xproj(const int* __restrict__ x,
                                               const float* __restrict__ embed,
                                               const float* __restrict__ wih_f,
                                               const float* __restrict__ wih_b,
                                               float* __restrict__ ws) {
    float* xp = ws + XP_OFF;
    const float* bias = ws + BIAS_OFF;
    __shared__ float As[BKC][68];   // [k][m], row stride 272B (16B aligned)
    __shared__ float Bs[BKC][68];   // [k][n]
    __shared__ int ids[64];
    const int bm = blockIdx.x;      // 0..255
    const int bn = blockIdx.y;      // 0..31
    const int tid = threadIdx.x;
    const int tx = tid & 15, ty = tid >> 4;

    if (tid < 64) {
        int r = bm * 64 + tid;
        int t = r >> 6, b = r & 63;
        ids[tid] = x[b * 256 + t];
    }
    __syncthreads();

    float acc[4][4];
#pragma unroll
    for (int i = 0; i < 4; ++i)
#pragma unroll
        for (int j = 0; j < 4; ++j) acc[i][j] = 0.f;

    const int lm = tid >> 2;          // 0..63 (row within tile)
    const int lks = (tid & 3) * 8;    // 0,8,16,24

    for (int k0 = 0; k0 < 256; k0 += BKC) {
        // A tile: gather embed rows
        {
            const float* src = embed + (size_t)ids[lm] * 256 + k0 + lks;
            float4 a0 = *reinterpret_cast<const float4*>(src);
            float4 a1 = *reinterpret_cast<const float4*>(src + 4);
            As[lks + 0][lm] = a0.x; As[lks + 1][lm] = a0.y;
            As[lks + 2][lm] = a0.z; As[lks + 3][lm] = a0.w;
            As[lks + 4][lm] = a1.x; As[lks + 5][lm] = a1.y;
            As[lks + 6][lm] = a1.z; As[lks + 7][lm] = a1.w;
        }
        // B tile
        {
            int gn = bn * 64 + lm;
            const float* wsrc = (gn < 1024) ? (wih_f + (size_t)gn * 256)
                                            : (wih_b + (size_t)(gn - 1024) * 256);
            const float* src = wsrc + k0 + lks;
            float4 b0 = *reinterpret_cast<const float4*>(src);
            float4 b1 = *reinterpret_cast<const float4*>(src + 4);
            Bs[lks + 0][lm] = b0.x; Bs[lks + 1][lm] = b0.y;
            Bs[lks + 2][lm] = b0.z; Bs[lks + 3][lm] = b0.w;
            Bs[lks + 4][lm] = b1.x; Bs[lks + 5][lm] = b1.y;
            Bs[lks + 6][lm] = b1.z; Bs[lks + 7][lm] = b1.w;
        }
        __syncthreads();
#pragma unroll
        for (int k = 0; k < BKC; ++k) {
            float4 a = *reinterpret_cast<const float4*>(&As[k][ty * 4]);
            float4 bq = *reinterpret_cast<const float4*>(&Bs[k][tx * 4]);
            acc[0][0] += a.x * bq.x; acc[0][1] += a.x * bq.y; acc[0][2] += a.x * bq.z; acc[0][3] += a.x * bq.w;
            acc[1][0] += a.y * bq.x; acc[1][1] += a.y * bq.y; acc[1][2] += a.y * bq.z; acc[1][3] += a.y * bq.w;
            acc[2][0] += a.z * bq.x; acc[2][1] += a.z * bq.y; acc[2][2] += a.z * bq.z; acc[2][3] += a.z * bq.w;
            acc[3][0] += a.w * bq.x; acc[3][1] += a.w * bq.y; acc[3][2] += a.w * bq.z; acc[3][3] += a.w * bq.w;
        }
        __syncthreads();
    }

    const int gm = bm * 64 + ty * 4;
    const int gn = bn * 64 + tx * 4;
#pragma unroll
    for (int i = 0; i < 4; ++i) {
        float4 o;
        o.x = acc[i][0] + bias[gn + 0];
        o.y = acc[i][1] + bias[gn + 1];
        o.z = acc[i][2] + bias[gn + 2];
        o.w = acc[i][3] + bias[gn + 3];
        *reinterpret_cast<float4*>(xp + (size_t)(gm + i) * 2048 + gn) = o;
    }
}

// ---------------------------------------------------------------------------
// Recurrence: 128 blocks = (dir, batch), 1024 threads (thread = gate g).
// Per step: acc = xproj + dot(w_hh[g,:], h_prev) via coalesced float4 weight
// stream; gate activations through LDS; threads 0..255 update c,h.
__global__ __launch_bounds__(1024) void k_rec(float* __restrict__ ws) {
    const float* xp = ws + XP_OFF;
    const float* wt = ws + WT_OFF;
    float* hs = ws + HS_OFF;
    const int dir = blockIdx.x >> 6;
    const int b = blockIdx.x & 63;
    const int g = threadIdx.x;

    __shared__ float hlds[256];
    __shared__ float gact[1024];

    const float4* wrow = reinterpret_cast<const float4*>(wt + (size_t)dir * 262144);

    if (g < 256) hlds[g] = 0.f;
    float c = 0.f;
    __syncthreads();

    for (int it = 0; it < 256; ++it) {
        const int tt = dir ? (255 - it) : it;
        float acc = xp[((size_t)tt * 64 + b) * 2048 + dir * 1024 + g];
#pragma unroll 8
        for (int k4 = 0; k4 < 64; ++k4) {
            float4 w = wrow[(size_t)k4 * 1024 + g];
            float4 h = *reinterpret_cast<const float4*>(&hlds[k4 * 4]);
            acc += w.x * h.x + w.y * h.y + w.z * h.z + w.w * h.w;
        }
        const int gt = g >> 8;   // 0:i 1:f 2:g 3:o
        float a = (gt == 2) ? tanhf(acc) : 1.f / (1.f + expf(-acc));
        gact[g] = a;
        __syncthreads();
        if (g < 256) {
            float newc = gact[g + 256] * c + gact[g] * gact[g + 512];
            c = newc;
            float h = gact[g + 768] * tanhf(newc);
            hlds[g] = h;
            hs[((size_t)tt * 64 + b) * 512 + dir * 256 + g] = h;
        }
        __syncthreads();
    }
}

// ---------------------------------------------------------------------------
// Emissions: em[r][j] = dot(hstore[r][0:512], w_out[j]) + b_out[j]
__global__ __launch_bounds__(256) void k_emis(const float* __restrict__ wout,
                                              const float* __restrict__ bout,
                                              float* __restrict__ ws) {
    const float* hs = ws + HS_OFF;
    float* em = ws + EM_OFF;
    __shared__ float wl[9][512];
    __shared__ float bl[9];
    const int tid = threadIdx.x;
    for (int i = tid; i < 9 * 512; i += 256) wl[i / 512][i % 512] = wout[i];
    if (tid < 9) bl[tid] = bout[tid];
    __syncthreads();

    const int r = blockIdx.x * 256 + tid;
    const float4* hrow = reinterpret_cast<const float4*>(hs + (size_t)r * 512);
    float acc[9];
#pragma unroll
    for (int j = 0; j < 9; ++j) acc[j] = bl[j];
    for (int k4 = 0; k4 < 128; ++k4) {
        float4 h = hrow[k4];
#pragma unroll
        for (int j = 0; j < 9; ++j) {
            float4 w = *reinterpret_cast<const float4*>(&wl[j][k4 * 4]);
            acc[j] += h.x * w.x + h.y * w.y + h.z * w.z + h.w * w.w;
        }
    }
#pragma unroll
    for (int j = 0; j < 9; ++j) em[(size_t)r * 9 + j] = acc[j];
}

// ---------------------------------------------------------------------------
// Viterbi: one block per batch, lanes 0..8 own tag columns. First-index
// argmax (strict >) matches jnp.argmax.
__global__ __launch_bounds__(64) void k_vit(const float* __restrict__ start,
                                            const float* __restrict__ endv,
                                            const float* __restrict__ trans,
                                            const float* __restrict__ ws_c,
                                            float* __restrict__ out) {
    const float* em = ws_c + EM_OFF;
    const int b = blockIdx.x;
    const int lane = threadIdx.x;
    __shared__ float tr[81];
    __shared__ float sc[9];
    __shared__ float ns[9];
    __shared__ int hist[256][9];

    // FIX (round 1): block has 64 threads; 81 > 64 needs a strided load.
    for (int i = lane; i < 81; i += 64) tr[i] = trans[i];
    if (lane < 9) sc[lane] = start[lane] + em[(size_t)b * 9 + lane];
    __syncthreads();

    for (int t = 1; t < 256; ++t) {
        if (lane < 9) {
            float e = em[((size_t)t * 64 + b) * 9 + lane];
            float best = -1e30f; int bi = 0;
#pragma unroll
            for (int i = 0; i < 9; ++i) {
                float v = sc[i] + tr[i * 9 + lane];
                if (v > best) { best = v; bi = i; }
            }
            ns[lane] = best + e;
            hist[t][lane] = bi;
        }
        __syncthreads();
        if (lane < 9) sc[lane] = ns[lane];
        __syncthreads();
    }

    if (lane == 0) {
        float best = -1e30f; int bi = 0;
        for (int j = 0; j < 9; ++j) {
            float v = sc[j] + endv[j];
            if (v > best) { best = v; bi = j; }
        }
        out[16384 + b] = best;
        int cur = bi;
        out[(size_t)b * 256 + 255] = (float)cur;
        for (int t = 255; t >= 1; --t) {
            cur = hist[t][cur];
            out[(size_t)b * 256 + t - 1] = (float)cur;
        }
    }
}

// ---------------------------------------------------------------------------
extern "C" void kernel_launch(void* const* d_in, const int* in_sizes, int n_in,
                              void* d_out, int out_size, void* d_ws, size_t ws_size,
                              hipStream_t stream) {
    (void)in_sizes; (void)n_in; (void)out_size; (void)ws_size;
    const int*   x       = (const int*)d_in[0];
    const float* embed   = (const float*)d_in[1];
    const float* w_ih_f  = (const float*)d_in[2];
    const float* w_hh_f  = (const float*)d_in[3];
    const float* b_ih_f  = (const float*)d_in[4];
    const float* b_hh_f  = (const float*)d_in[5];
    const float* w_ih_b  = (const float*)d_in[6];
    const float* w_hh_b  = (const float*)d_in[7];
    const float* b_ih_b  = (const float*)d_in[8];
    const float* b_hh_b  = (const float*)d_in[9];
    const float* w_out   = (const float*)d_in[10];
    const float* b_out   = (const float*)d_in[11];
    const float* crf_start = (const float*)d_in[12];
    const float* crf_end   = (const float*)d_in[13];
    const float* crf_trans = (const float*)d_in[14];
    float* ws  = (float*)d_ws;
    float* out = (float*)d_out;

    hipLaunchKernelGGL(k_prep, dim3(512), dim3(256), 0, stream,
                       w_hh_f, w_hh_b, b_ih_f, b_hh_f, b_ih_b, b_hh_b, ws);
    hipLaunchKernelGGL(k_xproj, dim3(256, 32), dim3(256), 0, stream,
                       x, embed, w_ih_f, w_ih_b, ws);
    hipLaunchKernelGGL(k_rec, dim3(128), dim3(1024), 0, stream, ws);
    hipLaunchKernelGGL(k_emis, dim3(64), dim3(256), 0, stream, w_out, b_out, ws);
    hipLaunchKernelGGL(k_vit, dim3(64), dim3(64), 0, stream,
                       crf_start, crf_end, crf_trans, ws, out);
}